// Round 17
// baseline (24.568 us; speedup 1.0000x reference)
//
#include <hip/hip_runtime.h>
#include <math.h>

typedef short bf16x8 __attribute__((ext_vector_type(8)));
typedef float f32x16 __attribute__((ext_vector_type(16)));
typedef unsigned int u32x4 __attribute__((ext_vector_type(4)));

#define B 16
#define N 4096
#define K 4096
#define OBJ_ELEMS (8*512*3)        // 12288 per batch
#define OBJ_VEC4  (OBJ_ELEMS/4)    // 3072 float4 per batch
#define NSEG 64
#define NCHUNK (N/NSEG)            // 64 adv rows per block (2 groups x 32)
#define BLK 512                    // 8 waves: 2 row-groups x 4 K-quarters
#define OBJ_V4_PER_BLK (OBJ_VEC4/NSEG) // 48 float4 per block
#define CD_W 0.2f
#define EPS_F 1e-7f

// ws layout (floats): csum[B*NSEG] @0, lsq[B*NSEG] @1024
#define CS_OFF 0
#define LS_OFF (B*NSEG)

__device__ __forceinline__ unsigned int cvt_pk_bf16(float lo, float hi) {
    unsigned int r;
    asm volatile("v_cvt_pk_bf16_f32 %0, %1, %2" : "=v"(r) : "v"(lo), "v"(hi));
    return r;
}

__global__ __launch_bounds__(BLK, 8) void chamfer_mfma_kernel(
    const float* __restrict__ adv, const float* __restrict__ ori,
    const float* __restrict__ adv_obj, const float* __restrict__ ori_obj,
    float* __restrict__ csum, float* __restrict__ lsq)
{
    __shared__ uint2 slds[K];              // 32 KB: ori bf16 {-2x,-2y | -2z,o2}
    __shared__ float rowmin[8][32];        // per-wave row-mins
    __shared__ float a2lds[NCHUNK];        // fp32 |a|^2 per row
    __shared__ float red_c, red_l;

    const int nseg = blockIdx.x;
    const int b    = blockIdx.y;
    const int tid  = threadIdx.x;
    const int wid  = tid >> 6;
    const int lane = tid & 63;
    const int col  = lane & 31;
    const int hi   = lane >> 5;
    const int rg   = wid & 1;              // row group (32 rows each, 2 groups)
    const int kh   = wid >> 1;             // K quarter (1024 ori points each)

    // --- stage + convert ori: 6 float4 loads -> 8 packed points per thread ---
    {
        const float4* src =
            reinterpret_cast<const float4*>(ori + (size_t)(b*K + tid*8)*3);
        float4 f0 = src[0], f1 = src[1], f2 = src[2];
        float4 f3 = src[3], f4 = src[4], f5 = src[5];
        float xs[8], ys[8], zs[8];
        xs[0]=f0.x; ys[0]=f0.y; zs[0]=f0.z;
        xs[1]=f0.w; ys[1]=f1.x; zs[1]=f1.y;
        xs[2]=f1.z; ys[2]=f1.w; zs[2]=f2.x;
        xs[3]=f2.y; ys[3]=f2.z; zs[3]=f2.w;
        xs[4]=f3.x; ys[4]=f3.y; zs[4]=f3.z;
        xs[5]=f3.w; ys[5]=f4.x; zs[5]=f4.y;
        xs[6]=f4.z; ys[6]=f4.w; zs[6]=f5.x;
        xs[7]=f5.y; ys[7]=f5.z; zs[7]=f5.w;
        #pragma unroll
        for (int j = 0; j < 8; ++j) {
            float x = xs[j], y = ys[j], z = zs[j];
            float o2 = x*x + y*y + z*z;
            uint2 e;
            e.x = cvt_pk_bf16(-2.f*x, -2.f*y);
            e.y = cvt_pk_bf16(-2.f*z, o2);
            slds[tid*8 + j] = e;
        }
    }

    // --- A fragment: this wave's 32 adv rows, K=4 in low half ---
    const int n = nseg*NCHUNK + rg*32 + col;
    const float* ap = adv + (b*N + n)*3;
    float ax = ap[0], ay = ap[1], az = ap[2];
    float a2 = ax*ax + ay*ay + az*az;
    if (kh == 0 && hi == 0) a2lds[rg*32 + col] = a2;
    unsigned int a01 = 0u, a23 = 0u;
    if (hi == 0) {
        a01 = cvt_pk_bf16(ax, ay);
        a23 = cvt_pk_bf16(az, 1.0f);
    }
    u32x4 aw = {a01, a23, 0u, 0u};
    bf16x8 afrag = __builtin_bit_cast(bf16x8, aw);

    __syncthreads();

    // --- main loop: this wave's 32 ori tiles of 32 points (K/4) ---
    f32x16 acc = {INFINITY,INFINITY,INFINITY,INFINITY,
                  INFINITY,INFINITY,INFINITY,INFINITY,
                  INFINITY,INFINITY,INFINITY,INFINITY,
                  INFINITY,INFINITY,INFINITY,INFINITY};
    const f32x16 zc = {0,0,0,0, 0,0,0,0, 0,0,0,0, 0,0,0,0};

    #pragma unroll 4
    for (int t = kh*32; t < kh*32 + 32; t += 2) {
        uint2 q0 = slds[t*32 + col];
        uint2 q1 = slds[(t+1)*32 + col];
        u32x4 w0 = {q0.x, q0.y, 0u, 0u};
        u32x4 w1 = {q1.x, q1.y, 0u, 0u};
        bf16x8 b0 = __builtin_bit_cast(bf16x8, w0);
        bf16x8 b1 = __builtin_bit_cast(bf16x8, w1);
        f32x16 c0 = __builtin_amdgcn_mfma_f32_32x32x16_bf16(afrag, b0, zc, 0,0,0);
        f32x16 c1 = __builtin_amdgcn_mfma_f32_32x32x16_bf16(afrag, b1, zc, 0,0,0);
        #pragma unroll
        for (int r = 0; r < 16; ++r)
            acc[r] = fminf(fminf(c0[r], c1[r]), acc[r]);   // v_min3_f32
    }

    // --- col-min (over ori dim) within each 32-lane half ---
    #pragma unroll
    for (int r = 0; r < 16; ++r) {
        float v = acc[r];
        v = fminf(v, __shfl_xor(v, 1));
        v = fminf(v, __shfl_xor(v, 2));
        v = fminf(v, __shfl_xor(v, 4));
        v = fminf(v, __shfl_xor(v, 8));
        v = fminf(v, __shfl_xor(v, 16));
        acc[r] = v;
    }
    if (col == 0) {   // lanes 0 and 32 publish 16 rows each
        #pragma unroll
        for (int r = 0; r < 16; ++r)
            rowmin[wid][(r&3) + 8*(r>>2) + 4*hi] = acc[r];
    }
    __syncthreads();

    // --- epilogue: combine 4 K-quarters, add a2; wave 1 folds obj-L2 ---
    float s = 0.f;
    if (wid == 0) {            // 64 threads: one adv row each
        int rg2 = lane >> 5, ri = lane & 31;
        float m = fminf(fminf(rowmin[rg2][ri],     rowmin[2 + rg2][ri]),
                        fminf(rowmin[4 + rg2][ri], rowmin[6 + rg2][ri]));
        s = m + a2lds[lane];
    } else if (wid == 1) {     // 48 of 64 threads: obj-L2 slice
        if (lane < OBJ_V4_PER_BLK) {
            int idx = b*OBJ_VEC4 + nseg*OBJ_V4_PER_BLK + lane;
            float4 a = reinterpret_cast<const float4*>(adv_obj)[idx];
            float4 o = reinterpret_cast<const float4*>(ori_obj)[idx];
            float dx = a.x - o.x, dy = a.y - o.y, dz = a.z - o.z, dw = a.w - o.w;
            s = dx*dx + dy*dy + dz*dz + dw*dw;
        }
    }
    #pragma unroll
    for (int off = 32; off; off >>= 1) s += __shfl_down(s, off);
    if (wid == 0 && lane == 0) red_c = s;
    if (wid == 1 && lane == 0) red_l = s;
    __syncthreads();
    if (tid == 0) csum[b*NSEG + nseg] = red_c;
    if (tid == 1) lsq [b*NSEG + nseg] = red_l;
}

__global__ __launch_bounds__(256) void final_kernel(
    const float* __restrict__ csum, const float* __restrict__ lsq,
    const float* __restrict__ w, float* __restrict__ out)
{
    const int tid = threadIdx.x;           // 256 threads, 4 partials each
    float c = 0.f, l = 0.f;
    #pragma unroll
    for (int j = 0; j < 4; ++j) {
        c += csum[4*tid + j];
        l += lsq [4*tid + j];
    }
    // each batch's 64 partials live in one 16-lane group
    #pragma unroll
    for (int off = 8; off; off >>= 1) {
        c += __shfl_down(c, off, 16);
        l += __shfl_down(l, off, 16);
    }
    __shared__ float sc[B], sl[B];
    int bb = tid >> 4;
    if ((tid & 15) == 0) { sc[bb] = c; sl[bb] = l; }
    __syncthreads();
    if (tid < 64) {
        float cc = 0.f, ll = 0.f;
        if (tid < B) {
            float wt = w[tid];
            cc = (sc[tid] / (float)N) * wt;
            ll = sqrtf(sl[tid] + EPS_F) * wt;
        }
        #pragma unroll
        for (int off = 8; off; off >>= 1) {
            cc += __shfl_down(cc, off);
            ll += __shfl_down(ll, off);
        }
        if (tid == 0) out[0] = ll / (float)B + CD_W * (cc / (float)B);
    }
}

extern "C" void kernel_launch(void* const* d_in, const int* in_sizes, int n_in,
                              void* d_out, int out_size, void* d_ws, size_t ws_size,
                              hipStream_t stream)
{
    const float* adv_pc  = (const float*)d_in[0];
    const float* ori_pc  = (const float*)d_in[1];
    const float* adv_obj = (const float*)d_in[2];
    const float* ori_obj = (const float*)d_in[3];
    const float* weights = (const float*)d_in[4];
    float* out = (float*)d_out;
    float* ws  = (float*)d_ws;

    float* csum = ws + CS_OFF;
    float* lsq  = ws + LS_OFF;

    // 1) fused MFMA chamfer: grid = (NSEG, B) = 1024 blocks of 512
    //    -> exactly 4 blocks/CU, 32 waves/CU = 8 waves/SIMD
    chamfer_mfma_kernel<<<dim3(NSEG, B), dim3(BLK), 0, stream>>>(
        adv_pc, ori_pc, adv_obj, ori_obj, csum, lsq);

    // 2) weighted final combine (1 block)
    final_kernel<<<dim3(1), dim3(256), 0, stream>>>(csum, lsq, weights, out);
}

// Round 18
// 24.457 us; speedup vs baseline: 1.0046x; 1.0046x over previous
//
#include <hip/hip_runtime.h>
#include <math.h>

typedef short bf16x8 __attribute__((ext_vector_type(8)));
typedef float f32x16 __attribute__((ext_vector_type(16)));
typedef unsigned int u32x4 __attribute__((ext_vector_type(4)));

#define B 16
#define N 4096
#define K 4096
#define OBJ_ELEMS (8*512*3)        // 12288 per batch
#define OBJ_VEC4  (OBJ_ELEMS/4)    // 3072 float4 per batch
#define NSEG 32
#define NCHUNK (N/NSEG)            // 128 adv rows per block (4 groups x 32)
#define BLK 512                    // 8 waves: 4 row-groups x 2 K-halves
#define CD_W 0.2f
#define EPS_F 1e-7f

__device__ __forceinline__ unsigned int cvt_pk_bf16(float lo, float hi) {
    unsigned int r;
    asm volatile("v_cvt_pk_bf16_f32 %0, %1, %2" : "=v"(r) : "v"(lo), "v"(hi));
    return r;
}

__global__ __launch_bounds__(BLK, 4) void chamfer_mfma_kernel(
    const float* __restrict__ adv, const float* __restrict__ ori,
    const float* __restrict__ adv_obj, const float* __restrict__ ori_obj,
    const float* __restrict__ w, float* __restrict__ out)
{
    __shared__ uint2 slds[K];              // 32 KB: ori bf16 {-2x,-2y | -2z,o2}
    __shared__ float rowmin[8][32];        // per-wave row-mins
    __shared__ float a2lds[NCHUNK];        // fp32 |a|^2 per row
    __shared__ float red_c[2], red_l[6];

    const int nseg = blockIdx.x;
    const int b    = blockIdx.y;
    const int tid  = threadIdx.x;
    const int wid  = tid >> 6;
    const int lane = tid & 63;
    const int col  = lane & 31;
    const int hi   = lane >> 5;
    const int rg   = wid & 3;              // row group (32 rows each)
    const int kh   = wid >> 2;             // K half (2048 ori points each)

    // --- stage + convert ori: 6 float4 loads -> 8 packed points per thread ---
    {
        const float4* src =
            reinterpret_cast<const float4*>(ori + (size_t)(b*K + tid*8)*3);
        float4 f0 = src[0], f1 = src[1], f2 = src[2];
        float4 f3 = src[3], f4 = src[4], f5 = src[5];
        float xs[8], ys[8], zs[8];
        xs[0]=f0.x; ys[0]=f0.y; zs[0]=f0.z;
        xs[1]=f0.w; ys[1]=f1.x; zs[1]=f1.y;
        xs[2]=f1.z; ys[2]=f1.w; zs[2]=f2.x;
        xs[3]=f2.y; ys[3]=f2.z; zs[3]=f2.w;
        xs[4]=f3.x; ys[4]=f3.y; zs[4]=f3.z;
        xs[5]=f3.w; ys[5]=f4.x; zs[5]=f4.y;
        xs[6]=f4.z; ys[6]=f4.w; zs[6]=f5.x;
        xs[7]=f5.y; ys[7]=f5.z; zs[7]=f5.w;
        #pragma unroll
        for (int j = 0; j < 8; ++j) {
            float x = xs[j], y = ys[j], z = zs[j];
            float o2 = x*x + y*y + z*z;
            uint2 e;
            e.x = cvt_pk_bf16(-2.f*x, -2.f*y);
            e.y = cvt_pk_bf16(-2.f*z, o2);
            slds[tid*8 + j] = e;
        }
    }

    // --- A fragment: this wave's 32 adv rows, K=4 in low half ---
    const int n = nseg*NCHUNK + rg*32 + col;
    const float* ap = adv + (b*N + n)*3;
    float ax = ap[0], ay = ap[1], az = ap[2];
    float a2 = ax*ax + ay*ay + az*az;
    if (kh == 0 && hi == 0) a2lds[rg*32 + col] = a2;
    unsigned int a01 = 0u, a23 = 0u;
    if (hi == 0) {
        a01 = cvt_pk_bf16(ax, ay);
        a23 = cvt_pk_bf16(az, 1.0f);
    }
    u32x4 aw = {a01, a23, 0u, 0u};
    bf16x8 afrag = __builtin_bit_cast(bf16x8, aw);

    __syncthreads();

    // --- main loop: 4 phases; each preloads 8 float4 (16 ori points) into
    //     registers, then runs 8 memory-free MFMA+min3 iterations ---
    f32x16 acc = {INFINITY,INFINITY,INFINITY,INFINITY,
                  INFINITY,INFINITY,INFINITY,INFINITY,
                  INFINITY,INFINITY,INFINITY,INFINITY,
                  INFINITY,INFINITY,INFINITY,INFINITY};
    const f32x16 zc = {0,0,0,0, 0,0,0,0, 0,0,0,0, 0,0,0,0};
    const float4* s4 = reinterpret_cast<const float4*>(slds);  // 2 pts/float4

    #pragma unroll
    for (int ph = 0; ph < 4; ++ph) {
        float4 f[8];
        #pragma unroll
        for (int j = 0; j < 8; ++j)
            f[j] = s4[(kh*32 + ph*8 + j)*32 + col];
        #pragma unroll
        for (int j = 0; j < 8; ++j) {
            u32x4 uu = __builtin_bit_cast(u32x4, f[j]);
            u32x4 w0 = {uu.x, uu.y, 0u, 0u};
            u32x4 w1 = {uu.z, uu.w, 0u, 0u};
            bf16x8 b0 = __builtin_bit_cast(bf16x8, w0);
            bf16x8 b1 = __builtin_bit_cast(bf16x8, w1);
            f32x16 c0 = __builtin_amdgcn_mfma_f32_32x32x16_bf16(afrag, b0, zc, 0,0,0);
            f32x16 c1 = __builtin_amdgcn_mfma_f32_32x32x16_bf16(afrag, b1, zc, 0,0,0);
            #pragma unroll
            for (int r = 0; r < 16; ++r)
                acc[r] = fminf(fminf(c0[r], c1[r]), acc[r]);   // v_min3_f32
        }
    }

    // --- col-min (over ori dim) within each 32-lane half ---
    #pragma unroll
    for (int r = 0; r < 16; ++r) {
        float v = acc[r];
        v = fminf(v, __shfl_xor(v, 1));
        v = fminf(v, __shfl_xor(v, 2));
        v = fminf(v, __shfl_xor(v, 4));
        v = fminf(v, __shfl_xor(v, 8));
        v = fminf(v, __shfl_xor(v, 16));
        acc[r] = v;
    }
    if (col == 0) {   // lanes 0 and 32 publish 16 rows each
        #pragma unroll
        for (int r = 0; r < 16; ++r)
            rowmin[wid][(r&3) + 8*(r>>2) + 4*hi] = acc[r];
    }
    __syncthreads();

    // --- epilogue: combine K-halves + a2 (waves 0-1); obj-L2 only in the
    //     nseg==0 block of each batch (waves 2-7, whole batch slice) ---
    float s = 0.f;
    if (wid < 2) {             // 128 threads: one adv row each
        int row = tid;         // 0..127
        int rg2 = row >> 5, ri = row & 31;
        float m = fminf(rowmin[rg2][ri], rowmin[4 + rg2][ri]);
        s = m + a2lds[row];
    } else if (nseg == 0) {    // 384 threads: 8 float4 each over the batch
        int i = (wid - 2)*64 + lane;     // 0..383
        #pragma unroll
        for (int j = 0; j < 8; ++j) {
            int idx = b*OBJ_VEC4 + i + j*384;
            float4 a = reinterpret_cast<const float4*>(adv_obj)[idx];
            float4 o = reinterpret_cast<const float4*>(ori_obj)[idx];
            float dx = a.x - o.x, dy = a.y - o.y, dz = a.z - o.z, dw = a.w - o.w;
            s += dx*dx + dy*dy + dz*dz + dw*dw;
        }
    }
    #pragma unroll
    for (int off = 32; off; off >>= 1) s += __shfl_down(s, off);
    if (lane == 0) {
        if (wid < 2) red_c[wid]     = s;
        else         red_l[wid - 2] = s;
    }
    __syncthreads();

    // --- direct scalar accumulation: one atomic per block (+1 for nseg==0) ---
    if (tid == 0) {
        float wt = w[b];
        float contrib = (red_c[0] + red_c[1]) * wt * (CD_W / ((float)B * (float)N));
        if (nseg == 0) {
            float lsum = red_l[0] + red_l[1] + red_l[2]
                       + red_l[3] + red_l[4] + red_l[5];
            contrib += sqrtf(lsum + EPS_F) * wt / (float)B;
        }
        atomicAdd(out, contrib);
    }
}

extern "C" void kernel_launch(void* const* d_in, const int* in_sizes, int n_in,
                              void* d_out, int out_size, void* d_ws, size_t ws_size,
                              hipStream_t stream)
{
    const float* adv_pc  = (const float*)d_in[0];
    const float* ori_pc  = (const float*)d_in[1];
    const float* adv_obj = (const float*)d_in[2];
    const float* ori_obj = (const float*)d_in[3];
    const float* weights = (const float*)d_in[4];
    float* out = (float*)d_out;

    // zero the scalar output each call (graph-capturable memset node)
    hipMemsetAsync(out, 0, sizeof(float), stream);

    // single fused kernel: MFMA chamfer + obj-L2 + direct atomic combine
    chamfer_mfma_kernel<<<dim3(NSEG, B), dim3(BLK), 0, stream>>>(
        adv_pc, ori_pc, adv_obj, ori_obj, weights, out);
}

// Round 19
// 23.380 us; speedup vs baseline: 1.0508x; 1.0461x over previous
//
#include <hip/hip_runtime.h>
#include <math.h>

typedef short bf16x8 __attribute__((ext_vector_type(8)));
typedef float f32x16 __attribute__((ext_vector_type(16)));
typedef unsigned int u32x4 __attribute__((ext_vector_type(4)));

#define B 16
#define N 4096
#define K 4096
#define OBJ_ELEMS (8*512*3)        // 12288 per batch
#define OBJ_VEC4  (OBJ_ELEMS/4)    // 3072 float4 per batch
#define NSEG 32
#define NCHUNK (N/NSEG)            // 128 adv rows per block (4 groups x 32)
#define BLK 512                    // 8 waves: 4 row-groups x 2 K-halves
#define OBJ_V4_PER_BLK (OBJ_VEC4/NSEG) // 96 float4 per block
#define CD_W 0.2f
#define EPS_F 1e-7f

// ws layout (floats): csum[B*NSEG] @0, lsq[B*NSEG] @512, packed bf16 @2048
#define CS_OFF 0
#define LS_OFF (B*NSEG)
#define PK_OFF 2048                // 8192 bytes -> 16B aligned

__device__ __forceinline__ unsigned int cvt_pk_bf16(float lo, float hi) {
    unsigned int r;
    asm volatile("v_cvt_pk_bf16_f32 %0, %1, %2" : "=v"(r) : "v"(lo), "v"(hi));
    return r;
}

__global__ __launch_bounds__(256) void pack_ori_kernel(
    const float* __restrict__ ori, uint2* __restrict__ packed)
{
    int i = blockIdx.x * 256 + threadIdx.x;   // [0, B*K)
    const float* s = ori + (size_t)i*3;
    float x = s[0], y = s[1], z = s[2];
    float o2 = x*x + y*y + z*z;
    uint2 e;
    e.x = cvt_pk_bf16(-2.f*x, -2.f*y);
    e.y = cvt_pk_bf16(-2.f*z, o2);
    packed[i] = e;
}

__global__ __launch_bounds__(BLK, 4) void chamfer_mfma_kernel(
    const float* __restrict__ adv, const uint2* __restrict__ packed,
    const float* __restrict__ adv_obj, const float* __restrict__ ori_obj,
    float* __restrict__ csum, float* __restrict__ lsq)
{
    __shared__ float rowmin[8][32];        // per-wave row-mins
    __shared__ float a2lds[NCHUNK];        // fp32 |a|^2 per row
    __shared__ float red_c[2], red_l[2];

    const int nseg = blockIdx.x;
    const int b    = blockIdx.y;
    const int tid  = threadIdx.x;
    const int wid  = tid >> 6;
    const int lane = tid & 63;
    const int col  = lane & 31;
    const int hi   = lane >> 5;
    const int rg   = wid & 3;              // row group (32 rows each)
    const int kh   = wid >> 2;             // K half (2048 ori points each)

    // --- A fragment: this wave's 32 adv rows, K=4 in low half ---
    const int n = nseg*NCHUNK + rg*32 + col;
    const float* ap = adv + (size_t)(b*N + n)*3;
    float ax = ap[0], ay = ap[1], az = ap[2];
    float a2 = ax*ax + ay*ay + az*az;
    if (kh == 0 && hi == 0) a2lds[rg*32 + col] = a2;
    unsigned int a01 = 0u, a23 = 0u;
    if (hi == 0) {
        a01 = cvt_pk_bf16(ax, ay);
        a23 = cvt_pk_bf16(az, 1.0f);
    }
    u32x4 aw = {a01, a23, 0u, 0u};
    bf16x8 afrag = __builtin_bit_cast(bf16x8, aw);

    // --- main loop: B tiles streamed from global (L2-resident), no LDS ---
    // pair-tile pt covers 64 ori points; lane col takes points pt*64+2col,+1
    f32x16 acc = {INFINITY,INFINITY,INFINITY,INFINITY,
                  INFINITY,INFINITY,INFINITY,INFINITY,
                  INFINITY,INFINITY,INFINITY,INFINITY,
                  INFINITY,INFINITY,INFINITY,INFINITY};
    const f32x16 zc = {0,0,0,0, 0,0,0,0, 0,0,0,0, 0,0,0,0};
    const u32x4* gb4 = reinterpret_cast<const u32x4*>(packed + (size_t)b*K);

    #pragma unroll
    for (int ph = 0; ph < 4; ++ph) {
        u32x4 f[8];
        #pragma unroll
        for (int j = 0; j < 8; ++j)
            f[j] = gb4[(kh*32 + ph*8 + j)*32 + col];   // global_load_dwordx4
        #pragma unroll
        for (int j = 0; j < 8; ++j) {
            u32x4 uu = f[j];
            u32x4 w0 = {uu.x, uu.y, 0u, 0u};
            u32x4 w1 = {uu.z, uu.w, 0u, 0u};
            bf16x8 b0 = __builtin_bit_cast(bf16x8, w0);
            bf16x8 b1 = __builtin_bit_cast(bf16x8, w1);
            f32x16 c0 = __builtin_amdgcn_mfma_f32_32x32x16_bf16(afrag, b0, zc, 0,0,0);
            f32x16 c1 = __builtin_amdgcn_mfma_f32_32x32x16_bf16(afrag, b1, zc, 0,0,0);
            #pragma unroll
            for (int r = 0; r < 16; ++r)
                acc[r] = fminf(fminf(c0[r], c1[r]), acc[r]);   // v_min3_f32
        }
    }

    // --- col-min (over ori dim) within each 32-lane half ---
    #pragma unroll
    for (int r = 0; r < 16; ++r) {
        float v = acc[r];
        v = fminf(v, __shfl_xor(v, 1));
        v = fminf(v, __shfl_xor(v, 2));
        v = fminf(v, __shfl_xor(v, 4));
        v = fminf(v, __shfl_xor(v, 8));
        v = fminf(v, __shfl_xor(v, 16));
        acc[r] = v;
    }
    if (col == 0) {   // lanes 0 and 32 publish 16 rows each
        #pragma unroll
        for (int r = 0; r < 16; ++r)
            rowmin[wid][(r&3) + 8*(r>>2) + 4*hi] = acc[r];
    }
    __syncthreads();

    // --- epilogue: combine K-halves, add a2; waves 2-3 fold obj-L2 ---
    float s = 0.f;
    if (wid < 2) {             // 128 threads: one adv row each
        int row = tid;         // 0..127
        int rg2 = row >> 5, ri = row & 31;
        float m = fminf(rowmin[rg2][ri], rowmin[4 + rg2][ri]);
        s = m + a2lds[row];
    } else if (wid < 4) {      // 96 of 128 threads: obj-L2 slice
        int li = (wid - 2)*64 + lane;
        if (li < OBJ_V4_PER_BLK) {
            int idx = b*OBJ_VEC4 + nseg*OBJ_V4_PER_BLK + li;
            float4 a = reinterpret_cast<const float4*>(adv_obj)[idx];
            float4 o = reinterpret_cast<const float4*>(ori_obj)[idx];
            float dx = a.x - o.x, dy = a.y - o.y, dz = a.z - o.z, dw = a.w - o.w;
            s = dx*dx + dy*dy + dz*dz + dw*dw;
        }
    }
    #pragma unroll
    for (int off = 32; off; off >>= 1) s += __shfl_down(s, off);
    if (lane == 0) {
        if (wid < 2)       red_c[wid]     = s;
        else if (wid < 4)  red_l[wid - 2] = s;
    }
    __syncthreads();
    if (tid == 0) csum[b*NSEG + nseg] = red_c[0] + red_c[1];
    if (tid == 1) lsq [b*NSEG + nseg] = red_l[0] + red_l[1];
}

__global__ __launch_bounds__(256) void final_kernel(
    const float* __restrict__ csum, const float* __restrict__ lsq,
    const float* __restrict__ w, float* __restrict__ out)
{
    const int tid = threadIdx.x;           // 256 threads, 2 partials each
    float c = csum[2*tid] + csum[2*tid + 1];
    float l = lsq [2*tid] + lsq [2*tid + 1];
    // 16 partial-pairs per batch live in one 16-lane group
    #pragma unroll
    for (int off = 8; off; off >>= 1) {
        c += __shfl_down(c, off, 16);
        l += __shfl_down(l, off, 16);
    }
    __shared__ float sc[B], sl[B];
    int bb = tid >> 4;
    if ((tid & 15) == 0) { sc[bb] = c; sl[bb] = l; }
    __syncthreads();
    if (tid < 64) {
        float cc = 0.f, ll = 0.f;
        if (tid < B) {
            float wt = w[tid];
            cc = (sc[tid] / (float)N) * wt;
            ll = sqrtf(sl[tid] + EPS_F) * wt;
        }
        #pragma unroll
        for (int off = 8; off; off >>= 1) {
            cc += __shfl_down(cc, off);
            ll += __shfl_down(ll, off);
        }
        if (tid == 0) out[0] = ll / (float)B + CD_W * (cc / (float)B);
    }
}

extern "C" void kernel_launch(void* const* d_in, const int* in_sizes, int n_in,
                              void* d_out, int out_size, void* d_ws, size_t ws_size,
                              hipStream_t stream)
{
    const float* adv_pc  = (const float*)d_in[0];
    const float* ori_pc  = (const float*)d_in[1];
    const float* adv_obj = (const float*)d_in[2];
    const float* ori_obj = (const float*)d_in[3];
    const float* weights = (const float*)d_in[4];
    float* out = (float*)d_out;
    float* ws  = (float*)d_ws;

    float* csum   = ws + CS_OFF;
    float* lsq    = ws + LS_OFF;
    uint2* packed = (uint2*)(ws + PK_OFF);

    // 1) pack ori -> bf16 {-2x,-2y | -2z,o2}, 512 KB L2-resident
    pack_ori_kernel<<<dim3(B*K/256), dim3(256), 0, stream>>>(ori_pc, packed);

    // 2) MFMA chamfer streaming B from L2 (no LDS staging, no pre-loop barrier)
    chamfer_mfma_kernel<<<dim3(NSEG, B), dim3(BLK), 0, stream>>>(
        adv_pc, packed, adv_obj, ori_obj, csum, lsq);

    // 3) weighted final combine (1 block)
    final_kernel<<<dim3(1), dim3(256), 0, stream>>>(csum, lsq, weights, out);
}

// Round 20
// 16.707 us; speedup vs baseline: 1.4705x; 1.3994x over previous
//
#include <hip/hip_runtime.h>
#include <math.h>

typedef short bf16x8 __attribute__((ext_vector_type(8)));
typedef float f32x16 __attribute__((ext_vector_type(16)));
typedef unsigned int u32x4 __attribute__((ext_vector_type(4)));

#define B 16
#define N 4096
#define K 4096
#define OBJ_ELEMS (8*512*3)        // 12288 per batch
#define OBJ_VEC4  (OBJ_ELEMS/4)    // 3072 float4 per batch
#define NSEG 32
#define NCHUNK (N/NSEG)            // 128 adv rows per block (4 groups x 32)
#define BLK 512                    // 8 waves: 4 row-groups x 2 K-halves
#define OBJ_V4_PER_BLK (OBJ_VEC4/NSEG) // 96 float4 per block
#define CD_W 0.2f
#define EPS_F 1e-7f

// ws layout (floats): csum[B*NSEG] @0, lsq[B*NSEG] @512
#define CS_OFF 0
#define LS_OFF (B*NSEG)

#define MIN3(a,b,c) fminf(fminf((a),(b)),(c))

__device__ __forceinline__ unsigned int cvt_pk_bf16(float lo, float hi) {
    unsigned int r;
    asm volatile("v_cvt_pk_bf16_f32 %0, %1, %2" : "=v"(r) : "v"(lo), "v"(hi));
    return r;
}

__global__ __launch_bounds__(BLK, 4) void chamfer_mfma_kernel(
    const float* __restrict__ adv, const float* __restrict__ ori,
    const float* __restrict__ adv_obj, const float* __restrict__ ori_obj,
    float* __restrict__ csum, float* __restrict__ lsq)
{
    __shared__ uint2 slds[K];              // 32 KB: ori bf16 {-2x,-2y | -2z,o2}
    __shared__ float rowmin[8][32];        // per-wave per-adv-col min (+a2)
    __shared__ float red_c[2], red_l[2];

    const int nseg = blockIdx.x;
    const int b    = blockIdx.y;
    const int tid  = threadIdx.x;
    const int wid  = tid >> 6;
    const int lane = tid & 63;
    const int col  = lane & 31;
    const int hi   = lane >> 5;
    const int rg   = wid & 3;              // row group (32 adv rows each)
    const int kh   = wid >> 2;             // K half (2048 ori points each)

    // --- stage + convert ori: 6 float4 loads -> 8 packed points per thread ---
    {
        const float4* src =
            reinterpret_cast<const float4*>(ori + (size_t)(b*K + tid*8)*3);
        float4 f0 = src[0], f1 = src[1], f2 = src[2];
        float4 f3 = src[3], f4 = src[4], f5 = src[5];
        float xs[8], ys[8], zs[8];
        xs[0]=f0.x; ys[0]=f0.y; zs[0]=f0.z;
        xs[1]=f0.w; ys[1]=f1.x; zs[1]=f1.y;
        xs[2]=f1.z; ys[2]=f1.w; zs[2]=f2.x;
        xs[3]=f2.y; ys[3]=f2.z; zs[3]=f2.w;
        xs[4]=f3.x; ys[4]=f3.y; zs[4]=f3.z;
        xs[5]=f3.w; ys[5]=f4.x; zs[5]=f4.y;
        xs[6]=f4.z; ys[6]=f4.w; zs[6]=f5.x;
        xs[7]=f5.y; ys[7]=f5.z; zs[7]=f5.w;
        #pragma unroll
        for (int j = 0; j < 8; ++j) {
            float x = xs[j], y = ys[j], z = zs[j];
            float o2 = x*x + y*y + z*z;
            uint2 e;
            e.x = cvt_pk_bf16(-2.f*x, -2.f*y);
            e.y = cvt_pk_bf16(-2.f*z, o2);
            slds[tid*8 + j] = e;
        }
    }

    // --- B fragment (adv): lane's col = its adv point, K=4 in low half ---
    const int n = nseg*NCHUNK + rg*32 + col;
    const float* ap = adv + (size_t)(b*N + n)*3;
    float ax = ap[0], ay = ap[1], az = ap[2];
    float a2 = ax*ax + ay*ay + az*az;      // stays in-register, added at end
    unsigned int a01 = 0u, a23 = 0u;
    if (hi == 0) {
        a01 = cvt_pk_bf16(ax, ay);
        a23 = cvt_pk_bf16(az, 1.0f);
    }
    u32x4 aw = {a01, a23, 0u, 0u};
    bf16x8 bfrag = __builtin_bit_cast(bf16x8, aw);

    __syncthreads();

    // --- main loop: A = ori tiles (rows), B = adv (cols). Min over ori is
    //     lane-local: per MFMA pair, tree-fold 32 reg values into scalar m ---
    float m = INFINITY;
    const f32x16 zc = {0,0,0,0, 0,0,0,0, 0,0,0,0, 0,0,0,0};
    const float4* s4 = reinterpret_cast<const float4*>(slds);  // 2 pts/float4

    #pragma unroll
    for (int ph = 0; ph < 4; ++ph) {
        float4 f[8];
        #pragma unroll
        for (int j = 0; j < 8; ++j)
            f[j] = s4[(kh*32 + ph*8 + j)*32 + col];
        #pragma unroll
        for (int j = 0; j < 8; ++j) {
            u32x4 uu = __builtin_bit_cast(u32x4, f[j]);
            u32x4 w0 = {uu.x, uu.y, 0u, 0u};
            u32x4 w1 = {uu.z, uu.w, 0u, 0u};
            bf16x8 t0 = __builtin_bit_cast(bf16x8, w0);   // A-frag: even points
            bf16x8 t1 = __builtin_bit_cast(bf16x8, w1);   // A-frag: odd points
            f32x16 c0 = __builtin_amdgcn_mfma_f32_32x32x16_bf16(t0, bfrag, zc, 0,0,0);
            f32x16 c1 = __builtin_amdgcn_mfma_f32_32x32x16_bf16(t1, bfrag, zc, 0,0,0);
            // tree-min of 32 values into m (16 v_min3, depth 4)
            #define V(i) ((i) < 16 ? c0[(i)] : c1[(i)-16])
            float g0 = MIN3(V(0),  V(1),  V(2));
            float g1 = MIN3(V(3),  V(4),  V(5));
            float g2 = MIN3(V(6),  V(7),  V(8));
            float g3 = MIN3(V(9),  V(10), V(11));
            float g4 = MIN3(V(12), V(13), V(14));
            float g5 = MIN3(V(15), V(16), V(17));
            float g6 = MIN3(V(18), V(19), V(20));
            float g7 = MIN3(V(21), V(22), V(23));
            float g8 = MIN3(V(24), V(25), V(26));
            float g9 = MIN3(V(27), V(28), V(29));
            float h0 = MIN3(g0, g1, g2);
            float h1 = MIN3(g3, g4, g5);
            float h2 = MIN3(g6, g7, g8);
            float h3 = MIN3(g9, V(30), V(31));
            m = MIN3(MIN3(h0, h1, h2), h3, m);
            #undef V
        }
    }

    // --- lane-local finish: combine hi/lo halves (one shuffle), add a2 ---
    m = fminf(m, __shfl_xor(m, 32));
    m += a2;
    if (hi == 0) rowmin[wid][col] = m;     // one b32 write per lo-lane
    __syncthreads();

    // --- epilogue: combine K-halves (waves 0-1); waves 2-3 fold obj-L2 ---
    float s = 0.f;
    if (wid < 2) {             // 128 threads: one adv row each
        int row = tid;         // 0..127
        int rg2 = row >> 5, ri = row & 31;
        s = fminf(rowmin[rg2][ri], rowmin[4 + rg2][ri]);
    } else if (wid < 4) {      // 96 of 128 threads: obj-L2 slice
        int li = (wid - 2)*64 + lane;
        if (li < OBJ_V4_PER_BLK) {
            int idx = b*OBJ_VEC4 + nseg*OBJ_V4_PER_BLK + li;
            float4 a = reinterpret_cast<const float4*>(adv_obj)[idx];
            float4 o = reinterpret_cast<const float4*>(ori_obj)[idx];
            float dx = a.x - o.x, dy = a.y - o.y, dz = a.z - o.z, dw = a.w - o.w;
            s = dx*dx + dy*dy + dz*dz + dw*dw;
        }
    }
    #pragma unroll
    for (int off = 32; off; off >>= 1) s += __shfl_down(s, off);
    if (lane == 0) {
        if (wid < 2)       red_c[wid]     = s;
        else if (wid < 4)  red_l[wid - 2] = s;
    }
    __syncthreads();
    if (tid == 0) csum[b*NSEG + nseg] = red_c[0] + red_c[1];
    if (tid == 1) lsq [b*NSEG + nseg] = red_l[0] + red_l[1];
}

__global__ __launch_bounds__(256) void final_kernel(
    const float* __restrict__ csum, const float* __restrict__ lsq,
    const float* __restrict__ w, float* __restrict__ out)
{
    const int tid = threadIdx.x;           // 256 threads, 2 partials each
    float c = csum[2*tid] + csum[2*tid + 1];
    float l = lsq [2*tid] + lsq [2*tid + 1];
    // 16 partial-pairs per batch live in one 16-lane group
    #pragma unroll
    for (int off = 8; off; off >>= 1) {
        c += __shfl_down(c, off, 16);
        l += __shfl_down(l, off, 16);
    }
    __shared__ float sc[B], sl[B];
    int bb = tid >> 4;
    if ((tid & 15) == 0) { sc[bb] = c; sl[bb] = l; }
    __syncthreads();
    if (tid < 64) {
        float cc = 0.f, ll = 0.f;
        if (tid < B) {
            float wt = w[tid];
            cc = (sc[tid] / (float)N) * wt;
            ll = sqrtf(sl[tid] + EPS_F) * wt;
        }
        #pragma unroll
        for (int off = 8; off; off >>= 1) {
            cc += __shfl_down(cc, off);
            ll += __shfl_down(ll, off);
        }
        if (tid == 0) out[0] = ll / (float)B + CD_W * (cc / (float)B);
    }
}

extern "C" void kernel_launch(void* const* d_in, const int* in_sizes, int n_in,
                              void* d_out, int out_size, void* d_ws, size_t ws_size,
                              hipStream_t stream)
{
    const float* adv_pc  = (const float*)d_in[0];
    const float* ori_pc  = (const float*)d_in[1];
    const float* adv_obj = (const float*)d_in[2];
    const float* ori_obj = (const float*)d_in[3];
    const float* weights = (const float*)d_in[4];
    float* out = (float*)d_out;
    float* ws  = (float*)d_ws;

    float* csum = ws + CS_OFF;
    float* lsq  = ws + LS_OFF;

    // 1) fused MFMA chamfer (swapped operands: lane-local min) + obj-L2:
    //    grid = (NSEG, B) = 512 blocks of 512
    chamfer_mfma_kernel<<<dim3(NSEG, B), dim3(BLK), 0, stream>>>(
        adv_pc, ori_pc, adv_obj, ori_obj, csum, lsq);

    // 2) weighted final combine (1 block)
    final_kernel<<<dim3(1), dim3(256), 0, stream>>>(csum, lsq, weights, out);
}

// Round 21
// 16.672 us; speedup vs baseline: 1.4736x; 1.0021x over previous
//
#include <hip/hip_runtime.h>
#include <math.h>

typedef short bf16x8 __attribute__((ext_vector_type(8)));
typedef float f32x16 __attribute__((ext_vector_type(16)));
typedef unsigned int u32x4 __attribute__((ext_vector_type(4)));

#define B 16
#define N 4096
#define K 4096
#define OBJ_ELEMS (8*512*3)        // 12288 per batch
#define OBJ_VEC4  (OBJ_ELEMS/4)    // 3072 float4 per batch
#define NSEG 32
#define NCHUNK (N/NSEG)            // 128 adv rows per block (2 groups x 64)
#define BLK 512                    // 8 waves: 2 adv-groups x 4 K-quarters
#define OBJ_V4_PER_BLK (OBJ_VEC4/NSEG) // 96 float4 per block
#define CD_W 0.2f
#define EPS_F 1e-7f

// ws layout (floats): csum[B*NSEG] @0, lsq[B*NSEG] @512
#define CS_OFF 0
#define LS_OFF (B*NSEG)

#define MIN3(a,b,c) fminf(fminf((a),(b)),(c))

__device__ __forceinline__ unsigned int cvt_pk_bf16(float lo, float hi) {
    unsigned int r;
    asm volatile("v_cvt_pk_bf16_f32 %0, %1, %2" : "=v"(r) : "v"(lo), "v"(hi));
    return r;
}

// tree-min of 32 MFMA outputs into m (16 v_min3, depth 4)
__device__ __forceinline__ float tree32(const f32x16& c0, const f32x16& c1,
                                        float m) {
    #define V(i) ((i) < 16 ? c0[(i)] : c1[(i)-16])
    float g0 = MIN3(V(0),  V(1),  V(2));
    float g1 = MIN3(V(3),  V(4),  V(5));
    float g2 = MIN3(V(6),  V(7),  V(8));
    float g3 = MIN3(V(9),  V(10), V(11));
    float g4 = MIN3(V(12), V(13), V(14));
    float g5 = MIN3(V(15), V(16), V(17));
    float g6 = MIN3(V(18), V(19), V(20));
    float g7 = MIN3(V(21), V(22), V(23));
    float g8 = MIN3(V(24), V(25), V(26));
    float g9 = MIN3(V(27), V(28), V(29));
    float h0 = MIN3(g0, g1, g2);
    float h1 = MIN3(g3, g4, g5);
    float h2 = MIN3(g6, g7, g8);
    float h3 = MIN3(g9, V(30), V(31));
    return MIN3(MIN3(h0, h1, h2), h3, m);
    #undef V
}

__global__ __launch_bounds__(BLK, 4) void chamfer_mfma_kernel(
    const float* __restrict__ adv, const float* __restrict__ ori,
    const float* __restrict__ adv_obj, const float* __restrict__ ori_obj,
    float* __restrict__ csum, float* __restrict__ lsq)
{
    __shared__ uint2 slds[K];              // 32 KB: ori bf16 {-2x,-2y | -2z,o2}
    __shared__ float rowmin[8][64];        // per-wave per-adv-col min (+a2)
    __shared__ float red_c[2], red_l[2];

    const int nseg = blockIdx.x;
    const int b    = blockIdx.y;
    const int tid  = threadIdx.x;
    const int wid  = tid >> 6;
    const int lane = tid & 63;
    const int col  = lane & 31;
    const int hi   = lane >> 5;
    const int rg   = wid & 1;              // adv group (64 rows each)
    const int kh   = wid >> 1;             // K quarter (1024 ori points each)

    // --- stage + convert ori: 6 float4 loads -> 8 packed points per thread ---
    {
        const float4* src =
            reinterpret_cast<const float4*>(ori + (size_t)(b*K + tid*8)*3);
        float4 f0 = src[0], f1 = src[1], f2 = src[2];
        float4 f3 = src[3], f4 = src[4], f5 = src[5];
        float xs[8], ys[8], zs[8];
        xs[0]=f0.x; ys[0]=f0.y; zs[0]=f0.z;
        xs[1]=f0.w; ys[1]=f1.x; zs[1]=f1.y;
        xs[2]=f1.z; ys[2]=f1.w; zs[2]=f2.x;
        xs[3]=f2.y; ys[3]=f2.z; zs[3]=f2.w;
        xs[4]=f3.x; ys[4]=f3.y; zs[4]=f3.z;
        xs[5]=f3.w; ys[5]=f4.x; zs[5]=f4.y;
        xs[6]=f4.z; ys[6]=f4.w; zs[6]=f5.x;
        xs[7]=f5.y; ys[7]=f5.z; zs[7]=f5.w;
        #pragma unroll
        for (int j = 0; j < 8; ++j) {
            float x = xs[j], y = ys[j], z = zs[j];
            float o2 = x*x + y*y + z*z;
            uint2 e;
            e.x = cvt_pk_bf16(-2.f*x, -2.f*y);
            e.y = cvt_pk_bf16(-2.f*z, o2);
            slds[tid*8 + j] = e;
        }
    }

    // --- two B fragments (adv): lane's cols = rg*64+col and rg*64+32+col ---
    const int n0 = nseg*NCHUNK + rg*64 + col;
    const float* ap0 = adv + (size_t)(b*N + n0)*3;
    const float* ap1 = ap0 + 32*3;
    float ax0 = ap0[0], ay0 = ap0[1], az0 = ap0[2];
    float ax1 = ap1[0], ay1 = ap1[1], az1 = ap1[2];
    float a2_0 = ax0*ax0 + ay0*ay0 + az0*az0;
    float a2_1 = ax1*ax1 + ay1*ay1 + az1*az1;
    unsigned int b00 = 0u, b01 = 0u, b10 = 0u, b11 = 0u;
    if (hi == 0) {
        b00 = cvt_pk_bf16(ax0, ay0);
        b01 = cvt_pk_bf16(az0, 1.0f);
        b10 = cvt_pk_bf16(ax1, ay1);
        b11 = cvt_pk_bf16(az1, 1.0f);
    }
    u32x4 bw0 = {b00, b01, 0u, 0u};
    u32x4 bw1 = {b10, b11, 0u, 0u};
    bf16x8 bfrag0 = __builtin_bit_cast(bf16x8, bw0);
    bf16x8 bfrag1 = __builtin_bit_cast(bf16x8, bw1);

    __syncthreads();

    // --- main loop: 16 iterations; 1 ds_read_b128 feeds 4 MFMAs ---
    float m0 = INFINITY, m1 = INFINITY;
    const f32x16 zc = {0,0,0,0, 0,0,0,0, 0,0,0,0, 0,0,0,0};
    const float4* s4 = reinterpret_cast<const float4*>(slds);  // 2 pts/float4

    #pragma unroll 4
    for (int t = kh*16; t < kh*16 + 16; ++t) {
        float4 q = s4[t*32 + col];
        u32x4 uu = __builtin_bit_cast(u32x4, q);
        u32x4 w0 = {uu.x, uu.y, 0u, 0u};
        u32x4 w1 = {uu.z, uu.w, 0u, 0u};
        bf16x8 t0 = __builtin_bit_cast(bf16x8, w0);   // A-frag: even points
        bf16x8 t1 = __builtin_bit_cast(bf16x8, w1);   // A-frag: odd points
        f32x16 c0 = __builtin_amdgcn_mfma_f32_32x32x16_bf16(t0, bfrag0, zc, 0,0,0);
        f32x16 c1 = __builtin_amdgcn_mfma_f32_32x32x16_bf16(t1, bfrag0, zc, 0,0,0);
        f32x16 c2 = __builtin_amdgcn_mfma_f32_32x32x16_bf16(t0, bfrag1, zc, 0,0,0);
        f32x16 c3 = __builtin_amdgcn_mfma_f32_32x32x16_bf16(t1, bfrag1, zc, 0,0,0);
        m0 = tree32(c0, c1, m0);
        m1 = tree32(c2, c3, m1);
    }

    // --- lane-local finish: fold hi/lo halves, add a2 ---
    m0 = fminf(m0, __shfl_xor(m0, 32)) + a2_0;
    m1 = fminf(m1, __shfl_xor(m1, 32)) + a2_1;
    if (hi == 0) {
        rowmin[wid][col]      = m0;
        rowmin[wid][32 + col] = m1;
    }
    __syncthreads();

    // --- epilogue: combine 4 K-quarters (waves 0-1); waves 2-3 fold obj-L2 ---
    float s = 0.f;
    if (wid < 2) {             // 128 threads: one adv row each
        int row = tid;         // 0..127
        int rg2 = row >> 6, ri = row & 63;
        s = fminf(fminf(rowmin[rg2][ri],     rowmin[2 + rg2][ri]),
                  fminf(rowmin[4 + rg2][ri], rowmin[6 + rg2][ri]));
    } else if (wid < 4) {      // 96 of 128 threads: obj-L2 slice
        int li = (wid - 2)*64 + lane;
        if (li < OBJ_V4_PER_BLK) {
            int idx = b*OBJ_VEC4 + nseg*OBJ_V4_PER_BLK + li;
            float4 a = reinterpret_cast<const float4*>(adv_obj)[idx];
            float4 o = reinterpret_cast<const float4*>(ori_obj)[idx];
            float dx = a.x - o.x, dy = a.y - o.y, dz = a.z - o.z, dw = a.w - o.w;
            s = dx*dx + dy*dy + dz*dz + dw*dw;
        }
    }
    #pragma unroll
    for (int off = 32; off; off >>= 1) s += __shfl_down(s, off);
    if (lane == 0) {
        if (wid < 2)       red_c[wid]     = s;
        else if (wid < 4)  red_l[wid - 2] = s;
    }
    __syncthreads();
    if (tid == 0) csum[b*NSEG + nseg] = red_c[0] + red_c[1];
    if (tid == 1) lsq [b*NSEG + nseg] = red_l[0] + red_l[1];
}

__global__ __launch_bounds__(256) void final_kernel(
    const float* __restrict__ csum, const float* __restrict__ lsq,
    const float* __restrict__ w, float* __restrict__ out)
{
    const int tid = threadIdx.x;           // 256 threads, 2 partials each
    float c = csum[2*tid] + csum[2*tid + 1];
    float l = lsq [2*tid] + lsq [2*tid + 1];
    // 16 partial-pairs per batch live in one 16-lane group
    #pragma unroll
    for (int off = 8; off; off >>= 1) {
        c += __shfl_down(c, off, 16);
        l += __shfl_down(l, off, 16);
    }
    __shared__ float sc[B], sl[B];
    int bb = tid >> 4;
    if ((tid & 15) == 0) { sc[bb] = c; sl[bb] = l; }
    __syncthreads();
    if (tid < 64) {
        float cc = 0.f, ll = 0.f;
        if (tid < B) {
            float wt = w[tid];
            cc = (sc[tid] / (float)N) * wt;
            ll = sqrtf(sl[tid] + EPS_F) * wt;
        }
        #pragma unroll
        for (int off = 8; off; off >>= 1) {
            cc += __shfl_down(cc, off);
            ll += __shfl_down(ll, off);
        }
        if (tid == 0) out[0] = ll / (float)B + CD_W * (cc / (float)B);
    }
}

extern "C" void kernel_launch(void* const* d_in, const int* in_sizes, int n_in,
                              void* d_out, int out_size, void* d_ws, size_t ws_size,
                              hipStream_t stream)
{
    const float* adv_pc  = (const float*)d_in[0];
    const float* ori_pc  = (const float*)d_in[1];
    const float* adv_obj = (const float*)d_in[2];
    const float* ori_obj = (const float*)d_in[3];
    const float* weights = (const float*)d_in[4];
    float* out = (float*)d_out;
    float* ws  = (float*)d_ws;

    float* csum = ws + CS_OFF;
    float* lsq  = ws + LS_OFF;

    // 1) fused MFMA chamfer (2 B-frags/wave: 1 ds_read feeds 4 MFMAs):
    //    grid = (NSEG, B) = 512 blocks of 512
    chamfer_mfma_kernel<<<dim3(NSEG, B), dim3(BLK), 0, stream>>>(
        adv_pc, ori_pc, adv_obj, ori_obj, csum, lsq);

    // 2) weighted final combine (1 block)
    final_kernel<<<dim3(1), dim3(256), 0, stream>>>(csum, lsq, weights, out);
}

// Round 22
// 16.516 us; speedup vs baseline: 1.4876x; 1.0095x over previous
//
#include <hip/hip_runtime.h>
#include <math.h>

typedef short bf16x8 __attribute__((ext_vector_type(8)));
typedef float f32x16 __attribute__((ext_vector_type(16)));
typedef unsigned int u32x4 __attribute__((ext_vector_type(4)));

#define B 16
#define N 4096
#define K 4096
#define OBJ_ELEMS (8*512*3)        // 12288 per batch
#define OBJ_VEC4  (OBJ_ELEMS/4)    // 3072 float4 per batch
#define NSEG 32
#define NCHUNK (N/NSEG)            // 128 adv rows per block (2 groups x 64)
#define BLK 512                    // 8 waves: 2 adv-groups x 4 K-quarters
#define OBJ_V4_PER_BLK (OBJ_VEC4/NSEG) // 96 float4 per block
#define CD_W 0.2f
#define EPS_F 1e-7f

// ws layout (floats): csum[B*NSEG] @0, lsq[B*NSEG] @512
#define CS_OFF 0
#define LS_OFF (B*NSEG)

#define MIN3(a,b,c) fminf(fminf((a),(b)),(c))

__device__ __forceinline__ unsigned int cvt_pk_bf16(float lo, float hi) {
    unsigned int r;
    asm volatile("v_cvt_pk_bf16_f32 %0, %1, %2" : "=v"(r) : "v"(lo), "v"(hi));
    return r;
}

// tree-min of 32 MFMA outputs into m (16 v_min3, depth 4)
__device__ __forceinline__ float tree32(const f32x16& c0, const f32x16& c1,
                                        float m) {
    #define V(i) ((i) < 16 ? c0[(i)] : c1[(i)-16])
    float g0 = MIN3(V(0),  V(1),  V(2));
    float g1 = MIN3(V(3),  V(4),  V(5));
    float g2 = MIN3(V(6),  V(7),  V(8));
    float g3 = MIN3(V(9),  V(10), V(11));
    float g4 = MIN3(V(12), V(13), V(14));
    float g5 = MIN3(V(15), V(16), V(17));
    float g6 = MIN3(V(18), V(19), V(20));
    float g7 = MIN3(V(21), V(22), V(23));
    float g8 = MIN3(V(24), V(25), V(26));
    float g9 = MIN3(V(27), V(28), V(29));
    float h0 = MIN3(g0, g1, g2);
    float h1 = MIN3(g3, g4, g5);
    float h2 = MIN3(g6, g7, g8);
    float h3 = MIN3(g9, V(30), V(31));
    return MIN3(MIN3(h0, h1, h2), h3, m);
    #undef V
}

__global__ __launch_bounds__(BLK, 4) void chamfer_mfma_kernel(
    const float* __restrict__ adv, const float* __restrict__ ori,
    const float* __restrict__ adv_obj, const float* __restrict__ ori_obj,
    float* __restrict__ csum, float* __restrict__ lsq)
{
    __shared__ uint2 slds[K];              // 32 KB: ori bf16 {-2x,-2y | -2z,o2}
    __shared__ float rowmin[8][64];        // per-wave per-adv-col min (+a2)
    __shared__ float red_c[2], red_l[2];

    const int nseg = blockIdx.x;
    const int b    = blockIdx.y;
    const int tid  = threadIdx.x;
    const int wid  = tid >> 6;
    const int lane = tid & 63;
    const int col  = lane & 31;
    const int hi   = lane >> 5;
    const int rg   = wid & 1;              // adv group (64 rows each)
    const int kh   = wid >> 1;             // K quarter (1024 ori points each)

    // --- stage + convert ori: 6 float4 loads -> 8 packed points per thread ---
    {
        const float4* src =
            reinterpret_cast<const float4*>(ori + (size_t)(b*K + tid*8)*3);
        float4 f0 = src[0], f1 = src[1], f2 = src[2];
        float4 f3 = src[3], f4 = src[4], f5 = src[5];
        float xs[8], ys[8], zs[8];
        xs[0]=f0.x; ys[0]=f0.y; zs[0]=f0.z;
        xs[1]=f0.w; ys[1]=f1.x; zs[1]=f1.y;
        xs[2]=f1.z; ys[2]=f1.w; zs[2]=f2.x;
        xs[3]=f2.y; ys[3]=f2.z; zs[3]=f2.w;
        xs[4]=f3.x; ys[4]=f3.y; zs[4]=f3.z;
        xs[5]=f3.w; ys[5]=f4.x; zs[5]=f4.y;
        xs[6]=f4.z; ys[6]=f4.w; zs[6]=f5.x;
        xs[7]=f5.y; ys[7]=f5.z; zs[7]=f5.w;
        #pragma unroll
        for (int j = 0; j < 8; ++j) {
            float x = xs[j], y = ys[j], z = zs[j];
            float o2 = x*x + y*y + z*z;
            uint2 e;
            e.x = cvt_pk_bf16(-2.f*x, -2.f*y);
            e.y = cvt_pk_bf16(-2.f*z, o2);
            slds[tid*8 + j] = e;
        }
    }

    // --- two B fragments (adv): lane's cols = rg*64+col and rg*64+32+col ---
    const int n0 = nseg*NCHUNK + rg*64 + col;
    const float* ap0 = adv + (size_t)(b*N + n0)*3;
    const float* ap1 = ap0 + 32*3;
    float ax0 = ap0[0], ay0 = ap0[1], az0 = ap0[2];
    float ax1 = ap1[0], ay1 = ap1[1], az1 = ap1[2];
    float a2_0 = ax0*ax0 + ay0*ay0 + az0*az0;
    float a2_1 = ax1*ax1 + ay1*ay1 + az1*az1;
    unsigned int b00 = 0u, b01 = 0u, b10 = 0u, b11 = 0u;
    if (hi == 0) {
        b00 = cvt_pk_bf16(ax0, ay0);
        b01 = cvt_pk_bf16(az0, 1.0f);
        b10 = cvt_pk_bf16(ax1, ay1);
        b11 = cvt_pk_bf16(az1, 1.0f);
    }
    u32x4 bw0 = {b00, b01, 0u, 0u};
    u32x4 bw1 = {b10, b11, 0u, 0u};
    bf16x8 bfrag0 = __builtin_bit_cast(bf16x8, bw0);
    bf16x8 bfrag1 = __builtin_bit_cast(bf16x8, bw1);

    __syncthreads();

    // --- main loop: depth-1 software pipeline: issue iter t+1's MFMAs
    //     before folding iter t's outputs (MFMA pipe busy during min-trees) ---
    float m0 = INFINITY, m1 = INFINITY;
    const f32x16 zc = {0,0,0,0, 0,0,0,0, 0,0,0,0, 0,0,0,0};
    const float4* s4 = reinterpret_cast<const float4*>(slds);  // 2 pts/float4
    const int base = kh*16;

    f32x16 c0, c1, c2, c3;
    {
        float4 q = s4[base*32 + col];
        u32x4 uu = __builtin_bit_cast(u32x4, q);
        u32x4 wa = {uu.x, uu.y, 0u, 0u};
        u32x4 wb = {uu.z, uu.w, 0u, 0u};
        bf16x8 ta = __builtin_bit_cast(bf16x8, wa);
        bf16x8 tb = __builtin_bit_cast(bf16x8, wb);
        c0 = __builtin_amdgcn_mfma_f32_32x32x16_bf16(ta, bfrag0, zc, 0,0,0);
        c1 = __builtin_amdgcn_mfma_f32_32x32x16_bf16(tb, bfrag0, zc, 0,0,0);
        c2 = __builtin_amdgcn_mfma_f32_32x32x16_bf16(ta, bfrag1, zc, 0,0,0);
        c3 = __builtin_amdgcn_mfma_f32_32x32x16_bf16(tb, bfrag1, zc, 0,0,0);
    }
    #pragma unroll
    for (int t = 1; t < 16; ++t) {
        float4 q = s4[(base + t)*32 + col];
        u32x4 uu = __builtin_bit_cast(u32x4, q);
        u32x4 wa = {uu.x, uu.y, 0u, 0u};
        u32x4 wb = {uu.z, uu.w, 0u, 0u};
        bf16x8 ta = __builtin_bit_cast(bf16x8, wa);
        bf16x8 tb = __builtin_bit_cast(bf16x8, wb);
        f32x16 n0 = __builtin_amdgcn_mfma_f32_32x32x16_bf16(ta, bfrag0, zc, 0,0,0);
        f32x16 n1 = __builtin_amdgcn_mfma_f32_32x32x16_bf16(tb, bfrag0, zc, 0,0,0);
        m0 = tree32(c0, c1, m0);   // fold prev pair A while next MFMAs run
        f32x16 n2 = __builtin_amdgcn_mfma_f32_32x32x16_bf16(ta, bfrag1, zc, 0,0,0);
        f32x16 n3 = __builtin_amdgcn_mfma_f32_32x32x16_bf16(tb, bfrag1, zc, 0,0,0);
        m1 = tree32(c2, c3, m1);   // fold prev pair B
        c0 = n0; c1 = n1; c2 = n2; c3 = n3;
    }
    m0 = tree32(c0, c1, m0);
    m1 = tree32(c2, c3, m1);

    // --- lane-local finish: fold hi/lo halves, add a2 ---
    m0 = fminf(m0, __shfl_xor(m0, 32)) + a2_0;
    m1 = fminf(m1, __shfl_xor(m1, 32)) + a2_1;
    if (hi == 0) {
        rowmin[wid][col]      = m0;
        rowmin[wid][32 + col] = m1;
    }
    __syncthreads();

    // --- epilogue: combine 4 K-quarters (waves 0-1); waves 2-3 fold obj-L2 ---
    float s = 0.f;
    if (wid < 2) {             // 128 threads: one adv row each
        int row = tid;         // 0..127
        int rg2 = row >> 6, ri = row & 63;
        s = fminf(fminf(rowmin[rg2][ri],     rowmin[2 + rg2][ri]),
                  fminf(rowmin[4 + rg2][ri], rowmin[6 + rg2][ri]));
    } else if (wid < 4) {      // 96 of 128 threads: obj-L2 slice
        int li = (wid - 2)*64 + lane;
        if (li < OBJ_V4_PER_BLK) {
            int idx = b*OBJ_VEC4 + nseg*OBJ_V4_PER_BLK + li;
            float4 a = reinterpret_cast<const float4*>(adv_obj)[idx];
            float4 o = reinterpret_cast<const float4*>(ori_obj)[idx];
            float dx = a.x - o.x, dy = a.y - o.y, dz = a.z - o.z, dw = a.w - o.w;
            s = dx*dx + dy*dy + dz*dz + dw*dw;
        }
    }
    #pragma unroll
    for (int off = 32; off; off >>= 1) s += __shfl_down(s, off);
    if (lane == 0) {
        if (wid < 2)       red_c[wid]     = s;
        else if (wid < 4)  red_l[wid - 2] = s;
    }
    __syncthreads();
    if (tid == 0) csum[b*NSEG + nseg] = red_c[0] + red_c[1];
    if (tid == 1) lsq [b*NSEG + nseg] = red_l[0] + red_l[1];
}

__global__ __launch_bounds__(256) void final_kernel(
    const float* __restrict__ csum, const float* __restrict__ lsq,
    const float* __restrict__ w, float* __restrict__ out)
{
    const int tid = threadIdx.x;           // 256 threads, 2 partials each
    float c = csum[2*tid] + csum[2*tid + 1];
    float l = lsq [2*tid] + lsq [2*tid + 1];
    // 16 partial-pairs per batch live in one 16-lane group
    #pragma unroll
    for (int off = 8; off; off >>= 1) {
        c += __shfl_down(c, off, 16);
        l += __shfl_down(l, off, 16);
    }
    __shared__ float sc[B], sl[B];
    int bb = tid >> 4;
    if ((tid & 15) == 0) { sc[bb] = c; sl[bb] = l; }
    __syncthreads();
    if (tid < 64) {
        float cc = 0.f, ll = 0.f;
        if (tid < B) {
            float wt = w[tid];
            cc = (sc[tid] / (float)N) * wt;
            ll = sqrtf(sl[tid] + EPS_F) * wt;
        }
        #pragma unroll
        for (int off = 8; off; off >>= 1) {
            cc += __shfl_down(cc, off);
            ll += __shfl_down(ll, off);
        }
        if (tid == 0) out[0] = ll / (float)B + CD_W * (cc / (float)B);
    }
}

extern "C" void kernel_launch(void* const* d_in, const int* in_sizes, int n_in,
                              void* d_out, int out_size, void* d_ws, size_t ws_size,
                              hipStream_t stream)
{
    const float* adv_pc  = (const float*)d_in[0];
    const float* ori_pc  = (const float*)d_in[1];
    const float* adv_obj = (const float*)d_in[2];
    const float* ori_obj = (const float*)d_in[3];
    const float* weights = (const float*)d_in[4];
    float* out = (float*)d_out;
    float* ws  = (float*)d_ws;

    float* csum = ws + CS_OFF;
    float* lsq  = ws + LS_OFF;

    // 1) fused MFMA chamfer (software-pipelined MFMA || min-tree):
    //    grid = (NSEG, B) = 512 blocks of 512
    chamfer_mfma_kernel<<<dim3(NSEG, B), dim3(BLK), 0, stream>>>(
        adv_pc, ori_pc, adv_obj, ori_obj, csum, lsq);

    // 2) weighted final combine (1 block)
    final_kernel<<<dim3(1), dim3(256), 0, stream>>>(csum, lsq, weights, out);
}